// Round 1
// baseline (265.240 us; speedup 1.0000x reference)
//
#include <hip/hip_runtime.h>
#include <hip/hip_bf16.h>

#define BATCH 16
#define CH    256
#define HW    1024
#define NH    4
#define DH    64
#define NG    32
#define CPG   8
#define EPSV  1e-6f

typedef __bf16 bf16x8 __attribute__((ext_vector_type(8)));
typedef float  f32x4  __attribute__((ext_vector_type(4)));

__device__ __forceinline__ unsigned short f2bf(float f) {
    union { __hip_bfloat16 h; unsigned short u; } cv;
    cv.h = __float2bfloat16(f);
    return cv.u;
}

// ---------------- prep: weight transpose fp32[c][d] -> bf16[n][c], bias concat ----
__global__ void prep_kernel(const float* Wq, const float* Wk, const float* Wv,
                            const float* Wp, const float* bq, const float* bk,
                            const float* bv, unsigned short* wqkv_t,
                            unsigned short* wp_t, float* bqkv) {
    int idx = blockIdx.x * 256 + threadIdx.x;
    if (idx < 768 * 256) {
        int n = idx >> 8, c = idx & 255;
        const float* W = (n < 256) ? Wq : (n < 512) ? Wk : Wv;
        int d = n & 255;
        wqkv_t[idx] = f2bf(W[c * 256 + d]);
    } else if (idx < 768 * 256 + 256 * 256) {
        int j = idx - 768 * 256;
        int n = j >> 8, c = j & 255;
        wp_t[j] = f2bf(Wp[c * 256 + n]);
    }
    if (idx < 768)
        bqkv[idx] = (idx < 256) ? bq[idx] : (idx < 512) ? bk[idx - 256] : bv[idx - 512];
}

// ---------------- GroupNorm pass 1: per (b,g) mean/rstd --------------------------
__global__ void gn_stats_kernel(const float* x, float* gmean, float* grstd) {
    int bg = blockIdx.x;                       // 0..511, group data is contiguous
    const float* p = x + (size_t)bg * (CPG * HW);
    int t = threadIdx.x;
    float s = 0.f, ss = 0.f;
    for (int i = t; i < CPG * HW; i += 256) {
        float v = p[i];
        s += v; ss += v * v;
    }
    for (int o = 32; o; o >>= 1) { s += __shfl_down(s, o); ss += __shfl_down(ss, o); }
    __shared__ float as[4], ass[4];
    int w = t >> 6;
    if ((t & 63) == 0) { as[w] = s; ass[w] = ss; }
    __syncthreads();
    if (t == 0) {
        float S = as[0] + as[1] + as[2] + as[3];
        float SS = ass[0] + ass[1] + ass[2] + ass[3];
        float mean = S / (float)(CPG * HW);
        float var = SS / (float)(CPG * HW) - mean * mean;
        gmean[bg] = mean;
        grstd[bg] = rsqrtf(var + EPSV);
    }
}

// ---------------- GroupNorm pass 2: normalize + transpose to xn_t[b][p][c] bf16 --
__global__ void gn_apply_kernel(const float* x, const float* scale, const float* bias,
                                const float* gmean, const float* grstd,
                                unsigned short* xn_t) {
    int b = blockIdx.y;
    int p0 = blockIdx.x * 64;
    int t = threadIdx.x;
    __shared__ unsigned short lds[64][CH + 8];     // row stride 264*2B = 16B-aligned
    int pp = t & 63, cq = t >> 6;
    const float* xb = x + (size_t)b * CH * HW;
    for (int c0 = 0; c0 < CH; c0 += 4) {
        int c = c0 + cq;
        int g = b * NG + (c >> 3);
        float m = gmean[g], r = grstd[g];
        float v = xb[(size_t)c * HW + p0 + pp];
        lds[pp][c] = f2bf((v - m) * r * scale[c] + bias[c]);
    }
    __syncthreads();
    unsigned short* dst = xn_t + ((size_t)b * HW + p0) * CH;
    for (int pass = 0; pass < 4; pass++) {
        int row = pass * 16 + (t >> 4);
        int c = (t & 15) * 16;
        ulonglong2 v0 = *reinterpret_cast<ulonglong2*>(&lds[row][c]);
        ulonglong2 v1 = *reinterpret_cast<ulonglong2*>(&lds[row][c + 8]);
        *reinterpret_cast<ulonglong2*>(dst + (size_t)row * CH + c) = v0;
        *reinterpret_cast<ulonglong2*>(dst + (size_t)row * CH + c + 8) = v1;
    }
}

// ---------------- QKV GEMM: (16384 x 256) x (256 x 768), bf16 MFMA ---------------
// A = xn_t[m][k] row-major; B = wqkv_t[n][k] row-major. 128x128/block, 64x64/wave.
__global__ __launch_bounds__(256) void qkv_kernel(const unsigned short* xn_t,
        const unsigned short* wqkv_t, const float* bqkv,
        unsigned short* qb, unsigned short* kb, unsigned short* vb) {
    int t = threadIdx.x;
    int wv = t >> 6, lane = t & 63, quad = lane >> 4, ln = lane & 15;
    int wr = wv >> 1, wc = wv & 1;
    int m0 = blockIdx.x * 128 + wr * 64;
    int n0 = blockIdx.y * 128 + wc * 64;

    f32x4 acc[4][4] = {};
    for (int k0 = 0; k0 < CH; k0 += 32) {
        int koff = k0 + quad * 8;
        bf16x8 af[4], bfr[4];
#pragma unroll
        for (int i = 0; i < 4; i++)
            af[i] = *reinterpret_cast<const bf16x8*>(xn_t + (size_t)(m0 + i * 16 + ln) * CH + koff);
#pragma unroll
        for (int j = 0; j < 4; j++)
            bfr[j] = *reinterpret_cast<const bf16x8*>(wqkv_t + (size_t)(n0 + j * 16 + ln) * CH + koff);
#pragma unroll
        for (int i = 0; i < 4; i++)
#pragma unroll
            for (int j = 0; j < 4; j++)
                acc[i][j] = __builtin_amdgcn_mfma_f32_16x16x32_bf16(af[i], bfr[j], acc[i][j], 0, 0, 0);
    }
#pragma unroll
    for (int j = 0; j < 4; j++) {
        int n = n0 + j * 16 + ln;
        float bias = bqkv[n];
        int which = n >> 8;              // uniform per 16-tile
        int dh_ = n & 255;
        int head = dh_ >> 6, d = dh_ & 63;
#pragma unroll
        for (int i = 0; i < 4; i++) {
            int mb = m0 + i * 16 + quad * 4;
            int bi = mb >> 10, p = mb & 1023;
            int bh = bi * NH + head;
            if (which < 2) {
                unsigned short* dst = (which == 0 ? qb : kb) + (size_t)bh * HW * DH;
#pragma unroll
                for (int r = 0; r < 4; r++)
                    dst[(size_t)(p + r) * DH + d] = f2bf(acc[i][j][r] + bias);
            } else {
                unsigned short* dst = vb + ((size_t)bh * DH + d) * HW + p;
                ushort4 pk4;
                pk4.x = f2bf(acc[i][j][0] + bias);
                pk4.y = f2bf(acc[i][j][1] + bias);
                pk4.z = f2bf(acc[i][j][2] + bias);
                pk4.w = f2bf(acc[i][j][3] + bias);
                *reinterpret_cast<ushort4*>(dst) = pk4;
            }
        }
    }
}

// ---------------- flash attention (transposed tiles) -----------------------------
// Per wave: 16 queries. S^T = K·Q^T (m=pk, n=pq=ln) -> online softmax (scalar
// state per lane) -> P^T via per-wave LDS -> O^T = V^T·P^T (m=d, n=pq=ln).
__global__ __launch_bounds__(256) void attn_kernel(const unsigned short* qb,
        const unsigned short* kb, const unsigned short* vb, unsigned short* h_t) {
    int qblk = blockIdx.x, bh = blockIdx.y;
    int t = threadIdx.x;
    int wv = t >> 6, lane = t & 63, quad = lane >> 4, ln = lane & 15;
    int q0 = qblk * 64 + wv * 16;

    const unsigned short* Q = qb + (size_t)bh * HW * DH;
    const unsigned short* K = kb + (size_t)bh * HW * DH;
    const unsigned short* V = vb + (size_t)bh * DH * HW;

    __shared__ unsigned short pbuf[4][16][72];   // per-wave P^T[pq][pk]

    bf16x8 qf[2];
#pragma unroll
    for (int kk = 0; kk < 2; kk++)
        qf[kk] = *reinterpret_cast<const bf16x8*>(Q + (size_t)(q0 + ln) * DH + kk * 32 + quad * 8);

    float mx = -1e30f, lsum = 0.f;
    f32x4 o[4] = {};

    for (int k0 = 0; k0 < HW; k0 += 64) {
        f32x4 s[4] = {};
#pragma unroll
        for (int mt = 0; mt < 4; mt++) {
            bf16x8 kf0 = *reinterpret_cast<const bf16x8*>(K + (size_t)(k0 + mt * 16 + ln) * DH + quad * 8);
            bf16x8 kf1 = *reinterpret_cast<const bf16x8*>(K + (size_t)(k0 + mt * 16 + ln) * DH + 32 + quad * 8);
            s[mt] = __builtin_amdgcn_mfma_f32_16x16x32_bf16(kf0, qf[0], s[mt], 0, 0, 0);
            s[mt] = __builtin_amdgcn_mfma_f32_16x16x32_bf16(kf1, qf[1], s[mt], 0, 0, 0);
        }
        float cm = -1e30f;
#pragma unroll
        for (int mt = 0; mt < 4; mt++)
#pragma unroll
            for (int r = 0; r < 4; r++) {
                s[mt][r] *= 0.0625f;             // 1/sqrt(C)
                cm = fmaxf(cm, s[mt][r]);
            }
        cm = fmaxf(cm, __shfl_xor(cm, 16));
        cm = fmaxf(cm, __shfl_xor(cm, 32));
        float mnew = fmaxf(mx, cm);
        float alpha = __expf(mx - mnew);
        mx = mnew;
        float rs = 0.f;
#pragma unroll
        for (int mt = 0; mt < 4; mt++)
#pragma unroll
            for (int r = 0; r < 4; r++) {
                float e = __expf(s[mt][r] - mnew);
                s[mt][r] = e;
                rs += e;
            }
        rs += __shfl_xor(rs, 16);
        rs += __shfl_xor(rs, 32);
        lsum = lsum * alpha + rs;
#pragma unroll
        for (int i = 0; i < 4; i++) {
            o[i][0] *= alpha; o[i][1] *= alpha; o[i][2] *= alpha; o[i][3] *= alpha;
        }
#pragma unroll
        for (int mt = 0; mt < 4; mt++)
#pragma unroll
            for (int r = 0; r < 4; r++)
                pbuf[wv][ln][mt * 16 + quad * 4 + r] = f2bf(s[mt][r]);
#pragma unroll
        for (int kk = 0; kk < 2; kk++) {
            bf16x8 pf = *reinterpret_cast<const bf16x8*>(&pbuf[wv][ln][kk * 32 + quad * 8]);
#pragma unroll
            for (int mt = 0; mt < 4; mt++) {
                bf16x8 vf = *reinterpret_cast<const bf16x8*>(V + (size_t)(mt * 16 + ln) * HW + k0 + kk * 32 + quad * 8);
                o[mt] = __builtin_amdgcn_mfma_f32_16x16x32_bf16(vf, pf, o[mt], 0, 0, 0);
            }
        }
    }
    float inv = 1.0f / lsum;
    int b = bh >> 2, head = bh & 3;
    unsigned short* dst = h_t + ((size_t)b * HW + q0 + ln) * CH + head * DH;
#pragma unroll
    for (int mt = 0; mt < 4; mt++) {
        ushort4 pk4;
        pk4.x = f2bf(o[mt][0] * inv);
        pk4.y = f2bf(o[mt][1] * inv);
        pk4.z = f2bf(o[mt][2] * inv);
        pk4.w = f2bf(o[mt][3] * inv);
        *reinterpret_cast<ushort4*>(dst + mt * 16 + quad * 4) = pk4;
    }
}

// ---------------- proj GEMM + bias + residual + /sqrt(2) -------------------------
__global__ __launch_bounds__(256) void proj_kernel(const unsigned short* h_t,
        const unsigned short* wp_t, const float* bp, const float* x, float* out) {
    int t = threadIdx.x;
    int wv = t >> 6, lane = t & 63, quad = lane >> 4, ln = lane & 15;
    int wr = wv >> 1, wc = wv & 1;
    int m0 = blockIdx.x * 128 + wr * 64;
    int n0 = blockIdx.y * 128 + wc * 64;

    f32x4 acc[4][4] = {};
    for (int k0 = 0; k0 < CH; k0 += 32) {
        int koff = k0 + quad * 8;
        bf16x8 af[4], bfr[4];
#pragma unroll
        for (int i = 0; i < 4; i++)
            af[i] = *reinterpret_cast<const bf16x8*>(h_t + (size_t)(m0 + i * 16 + ln) * CH + koff);
#pragma unroll
        for (int j = 0; j < 4; j++)
            bfr[j] = *reinterpret_cast<const bf16x8*>(wp_t + (size_t)(n0 + j * 16 + ln) * CH + koff);
#pragma unroll
        for (int i = 0; i < 4; i++)
#pragma unroll
            for (int j = 0; j < 4; j++)
                acc[i][j] = __builtin_amdgcn_mfma_f32_16x16x32_bf16(af[i], bfr[j], acc[i][j], 0, 0, 0);
    }
    const float inv_s2 = 0.70710678118654752440f;
#pragma unroll
    for (int j = 0; j < 4; j++) {
        int n = n0 + j * 16 + ln;
        float bias = bp[n];
#pragma unroll
        for (int i = 0; i < 4; i++) {
            int mb = m0 + i * 16 + quad * 4;
            int bi = mb >> 10, p = mb & 1023;
            size_t off = ((size_t)(bi * CH + n)) * HW + p;
            float4 xv = *reinterpret_cast<const float4*>(x + off);
            float4 ov;
            ov.x = (xv.x + acc[i][j][0] + bias) * inv_s2;
            ov.y = (xv.y + acc[i][j][1] + bias) * inv_s2;
            ov.z = (xv.z + acc[i][j][2] + bias) * inv_s2;
            ov.w = (xv.w + acc[i][j][3] + bias) * inv_s2;
            *reinterpret_cast<float4*>(out + off) = ov;
        }
    }
}

extern "C" void kernel_launch(void* const* d_in, const int* in_sizes, int n_in,
                              void* d_out, int out_size, void* d_ws, size_t ws_size,
                              hipStream_t stream) {
    const float* x        = (const float*)d_in[0];
    const float* gn_scale = (const float*)d_in[1];
    const float* gn_bias  = (const float*)d_in[2];
    const float* Wq = (const float*)d_in[3];
    const float* bq = (const float*)d_in[4];
    const float* Wk = (const float*)d_in[5];
    const float* bk = (const float*)d_in[6];
    const float* Wv = (const float*)d_in[7];
    const float* bv = (const float*)d_in[8];
    const float* Wp = (const float*)d_in[9];
    const float* bp = (const float*)d_in[10];
    float* out = (float*)d_out;

    char* ws = (char*)d_ws;
    // ws layout (bytes); h_t aliases xn_t (xn_t dead after qkv_kernel). Total ~32.5 MB.
    float*          gmean  = (float*)(ws + 0);
    float*          grstd  = (float*)(ws + 2048);
    float*          bqkv   = (float*)(ws + 4096);
    unsigned short* wqkv_t = (unsigned short*)(ws + 8192);
    unsigned short* wp_t   = (unsigned short*)(ws + 401408);
    unsigned short* xn_t   = (unsigned short*)(ws + 532480);
    unsigned short* h_t    = xn_t;
    unsigned short* qb     = (unsigned short*)(ws + 8921088);
    unsigned short* kb     = (unsigned short*)(ws + 17309696);
    unsigned short* vb     = (unsigned short*)(ws + 25698304);

    prep_kernel<<<1024, 256, 0, stream>>>(Wq, Wk, Wv, Wp, bq, bk, bv, wqkv_t, wp_t, bqkv);
    gn_stats_kernel<<<512, 256, 0, stream>>>(x, gmean, grstd);
    gn_apply_kernel<<<dim3(16, 16), 256, 0, stream>>>(x, gn_scale, gn_bias, gmean, grstd, xn_t);
    qkv_kernel<<<dim3(128, 6), 256, 0, stream>>>(xn_t, wqkv_t, bqkv, qb, kb, vb);
    attn_kernel<<<dim3(16, 64), 256, 0, stream>>>(qb, kb, vb, h_t);
    proj_kernel<<<dim3(128, 2), 256, 0, stream>>>(h_t, wp_t, bp, x, out);
}